// Round 1
// baseline (1863.461 us; speedup 1.0000x reference)
//
#include <hip/hip_runtime.h>
#include <stdint.h>

typedef __bf16 bf16;
typedef __bf16 bf16x8 __attribute__((ext_vector_type(8)));
typedef __bf16 bf16x4 __attribute__((ext_vector_type(4)));
typedef float f32x4 __attribute__((ext_vector_type(4)));

#define NNODES 100000
#define NEDGES 1600000

static __device__ __forceinline__ float bflo(uint32_t u) { return __uint_as_float(u << 16); }
static __device__ __forceinline__ float bfhi(uint32_t u) { return __uint_as_float(u & 0xffff0000u); }

// ---------------- init / conversion ----------------

__global__ __launch_bounds__(256) void k_zero(int* __restrict__ cursor, float* __restrict__ stats,
                                              int n, int nstats) {
    int i = blockIdx.x * 256 + threadIdx.x;
    if (i < n) cursor[i] = 0;
    if (i < nstats) stats[i] = 0.f;
}

__global__ __launch_bounds__(256) void k_cvt_x(const float* __restrict__ x, bf16* __restrict__ h, int n4) {
    int i = blockIdx.x * 256 + threadIdx.x;
    if (i >= n4) return;
    float4 v = ((const float4*)x)[i];
    bf16x4 o = {(bf16)v.x, (bf16)v.y, (bf16)v.z, (bf16)v.w};
    *(bf16x4*)(h + 4 * (size_t)i) = o;
}

// dst[0..n) = bf16(Wl), dst[n..2n) = bf16(Wr)
__global__ __launch_bounds__(256) void k_cvt_w(const float* __restrict__ wl, const float* __restrict__ wr,
                                               bf16* __restrict__ dst, int n) {
    int i = blockIdx.x * 256 + threadIdx.x;
    if (i >= n) return;
    dst[i] = (bf16)wl[i];
    dst[n + i] = (bf16)wr[i];
}

// ---------------- CSR build ----------------

__global__ __launch_bounds__(256) void k_count(const int* __restrict__ dst, int* __restrict__ deg, int E) {
    int e = blockIdx.x * 256 + threadIdx.x;
    if (e < E) atomicAdd(&deg[dst[e]], 1);
}

// exclusive scan, 256-element blocks; covers N+1 outputs (deg[i>=N] treated 0)
__global__ __launch_bounds__(256) void k_scan1(const int* __restrict__ deg, int* __restrict__ rowptr,
                                               int* __restrict__ bsum, int N) {
    __shared__ int sh[256];
    int i = blockIdx.x * 256 + threadIdx.x;
    int v = (i < N) ? deg[i] : 0;
    sh[threadIdx.x] = v;
    for (int off = 1; off < 256; off <<= 1) {
        __syncthreads();
        int t = (threadIdx.x >= off) ? sh[threadIdx.x - off] : 0;
        __syncthreads();
        sh[threadIdx.x] += t;
    }
    __syncthreads();
    if (i <= N) rowptr[i] = sh[threadIdx.x] - v;
    if (threadIdx.x == 255) bsum[blockIdx.x] = sh[255];
}

__global__ __launch_bounds__(512) void k_scan2(int* __restrict__ bsum, int nb) {
    __shared__ int sh[512];
    int v = (threadIdx.x < nb) ? bsum[threadIdx.x] : 0;
    sh[threadIdx.x] = v;
    for (int off = 1; off < 512; off <<= 1) {
        __syncthreads();
        int t = (threadIdx.x >= off) ? sh[threadIdx.x - off] : 0;
        __syncthreads();
        sh[threadIdx.x] += t;
    }
    __syncthreads();
    if (threadIdx.x < nb) bsum[threadIdx.x] = sh[threadIdx.x] - v;  // exclusive, in place
}

__global__ __launch_bounds__(256) void k_scan3(int* __restrict__ rowptr, const int* __restrict__ bsum,
                                               int* __restrict__ cursor, int N) {
    int i = blockIdx.x * 256 + threadIdx.x;
    if (i <= N) {
        int v = rowptr[i] + bsum[i >> 8];
        rowptr[i] = v;
        if (i < N) cursor[i] = v;
    }
}

__global__ __launch_bounds__(256) void k_scatter(const int* __restrict__ src, const int* __restrict__ dst,
                                                 int* __restrict__ cursor, int* __restrict__ ssrc, int E) {
    int e = blockIdx.x * 256 + threadIdx.x;
    if (e < E) {
        int d = dst[e];
        int pos = atomicAdd(&cursor[d], 1);
        ssrc[pos] = src[e];
    }
}

// ---------------- GEMM: P = X@Wl^T (bf16), R = X@Wr^T + bl (f32) ----------------
// W = [Wl ; Wr] as [2*Cout][128] bf16 row-major. One wave = 16 nodes x all cols.

__global__ __launch_bounds__(256) void k_gemm(const bf16* __restrict__ X, const bf16* __restrict__ W,
                                              const float* __restrict__ bl, bf16* __restrict__ P,
                                              float* __restrict__ R, int Cout, int N) {
    int wv = blockIdx.x * 4 + (threadIdx.x >> 6);
    int lane = threadIdx.x & 63;
    int node0 = wv * 16;
    if (node0 >= N) return;
    int m = lane & 15, quad = lane >> 4;
    const bf16* xr = X + (size_t)(node0 + m) * 128 + quad * 8;
    bf16x8 a0 = *(const bf16x8*)(xr);
    bf16x8 a1 = *(const bf16x8*)(xr + 32);
    bf16x8 a2 = *(const bf16x8*)(xr + 64);
    bf16x8 a3 = *(const bf16x8*)(xr + 96);
    int ntiles = (2 * Cout) >> 4;
    for (int ct = 0; ct < ntiles; ct++) {
        const bf16* wr = W + (size_t)(ct * 16 + m) * 128 + quad * 8;
        f32x4 acc = {0.f, 0.f, 0.f, 0.f};
        acc = __builtin_amdgcn_mfma_f32_16x16x32_bf16(a0, *(const bf16x8*)(wr), acc, 0, 0, 0);
        acc = __builtin_amdgcn_mfma_f32_16x16x32_bf16(a1, *(const bf16x8*)(wr + 32), acc, 0, 0, 0);
        acc = __builtin_amdgcn_mfma_f32_16x16x32_bf16(a2, *(const bf16x8*)(wr + 64), acc, 0, 0, 0);
        acc = __builtin_amdgcn_mfma_f32_16x16x32_bf16(a3, *(const bf16x8*)(wr + 96), acc, 0, 0, 0);
        // D mapping: col = lane&15, node = node0 + quad*4 + reg
        int col = (ct << 4) + m;
        if (col < Cout) {
            bf16* pp = P + (size_t)(node0 + quad * 4) * Cout + col;
            pp[0] = (bf16)acc[0];
            pp[Cout] = (bf16)acc[1];
            pp[2 * Cout] = (bf16)acc[2];
            pp[3 * Cout] = (bf16)acc[3];
        } else {
            int c2 = col - Cout;
            float bb = bl[c2];
            float* rr = R + (size_t)(node0 + quad * 4) * Cout + c2;
            rr[0] = acc[0] + bb;
            rr[Cout] = acc[1] + bb;
            rr[2 * Cout] = acc[2] + bb;
            rr[3 * Cout] = acc[3] + bb;
        }
    }
}

// ---------------- aggregate: o[n] = mean_{e in CSR[n]} P[src] + R[n]; BN partial stats ----------------
// one wave per node (grid-stride); lane handles cols 2*lane, 2*lane+1

__global__ __launch_bounds__(256) void k_aggregate(const bf16* __restrict__ p, const float* __restrict__ r,
                                                   const int* __restrict__ rowptr, const int* __restrict__ ssrc,
                                                   float* __restrict__ o, float* __restrict__ ssum,
                                                   float* __restrict__ ssq, int Cout, int N, int nwaves) {
    int wv = (blockIdx.x * 256 + threadIdx.x) >> 6;
    int lane = threadIdx.x & 63;
    int c0 = 2 * lane;
    bool act = c0 < Cout;
    int cc = act ? c0 : (Cout - 2);
    const uint32_t* pbase = (const uint32_t*)p;
    int rs = Cout >> 1;       // row stride in uints
    int co = cc >> 1;         // col offset in uints
    float s0 = 0.f, s1 = 0.f, q0 = 0.f, q1 = 0.f;
    for (int n = wv; n < N; n += nwaves) {
        int e0 = rowptr[n], e1 = rowptr[n + 1];
        float a0 = 0.f, a1 = 0.f;
        int e = e0;
        for (; e + 4 <= e1; e += 4) {
            int i0 = ssrc[e], i1 = ssrc[e + 1], i2 = ssrc[e + 2], i3 = ssrc[e + 3];
            uint32_t u0 = pbase[(size_t)i0 * rs + co];
            uint32_t u1 = pbase[(size_t)i1 * rs + co];
            uint32_t u2 = pbase[(size_t)i2 * rs + co];
            uint32_t u3 = pbase[(size_t)i3 * rs + co];
            a0 += bflo(u0) + bflo(u1) + bflo(u2) + bflo(u3);
            a1 += bfhi(u0) + bfhi(u1) + bfhi(u2) + bfhi(u3);
        }
        for (; e < e1; e++) {
            uint32_t u0 = pbase[(size_t)ssrc[e] * rs + co];
            a0 += bflo(u0);
            a1 += bfhi(u0);
        }
        int d = e1 - e0;
        float sc = 1.0f / (float)(d > 0 ? d : 1);
        size_t ro = (size_t)n * Cout + cc;
        float o0 = a0 * sc + r[ro];
        float o1 = a1 * sc + r[ro + 1];
        if (act) {
            o[ro] = o0;
            o[ro + 1] = o1;
            s0 += o0; s1 += o1;
            q0 += o0 * o0; q1 += o1 * o1;
        }
    }
    if (act) {
        atomicAdd(&ssum[c0], s0);
        atomicAdd(&ssum[c0 + 1], s1);
        atomicAdd(&ssq[c0], q0);
        atomicAdd(&ssq[c0 + 1], q1);
    }
}

// ---------------- BN finalize + normalize ----------------

__global__ __launch_bounds__(128) void k_bn_fin(const float* __restrict__ ssum, const float* __restrict__ ssq,
                                                const float* __restrict__ gamma, const float* __restrict__ beta,
                                                float* __restrict__ cA, float* __restrict__ cB, int Cout, int N) {
    int c = threadIdx.x;
    if (c >= Cout) return;
    float m = ssum[c] / (float)N;
    float var = ssq[c] / (float)N - m * m;
    float a = gamma[c] * rsqrtf(var + 1e-5f);
    cA[c] = a;
    cB[c] = beta[c] - m * a;
}

// o -> h (bf16), relu, C=128
__global__ __launch_bounds__(256) void k_norm_relu(const float* __restrict__ o, const float* __restrict__ cA,
                                                   const float* __restrict__ cB, bf16* __restrict__ h, int n4) {
    int i = blockIdx.x * 256 + threadIdx.x;
    if (i >= n4) return;
    float4 v = ((const float4*)o)[i];
    int c = (i * 4) & 127;
    float4 a = *(const float4*)(cA + c);
    float4 b = *(const float4*)(cB + c);
    float r0 = fmaxf(fmaf(v.x, a.x, b.x), 0.f);
    float r1 = fmaxf(fmaf(v.y, a.y, b.y), 0.f);
    float r2 = fmaxf(fmaf(v.z, a.z, b.z), 0.f);
    float r3 = fmaxf(fmaf(v.w, a.w, b.w), 0.f);
    bf16x4 ov = {(bf16)r0, (bf16)r1, (bf16)r2, (bf16)r3};
    *(bf16x4*)(h + 4 * (size_t)i) = ov;
}

// o -> d_out (f32), no relu, C=64
__global__ __launch_bounds__(256) void k_norm_out(const float* __restrict__ o, const float* __restrict__ cA,
                                                  const float* __restrict__ cB, float* __restrict__ out, int n4) {
    int i = blockIdx.x * 256 + threadIdx.x;
    if (i >= n4) return;
    float4 v = ((const float4*)o)[i];
    int c = (i * 4) & 63;
    float4 a = *(const float4*)(cA + c);
    float4 b = *(const float4*)(cB + c);
    float4 ov;
    ov.x = fmaf(v.x, a.x, b.x);
    ov.y = fmaf(v.y, a.y, b.y);
    ov.z = fmaf(v.z, a.z, b.z);
    ov.w = fmaf(v.w, a.w, b.w);
    ((float4*)out)[i] = ov;
}

// ---------------- launch ----------------

static inline int cdiv(int a, int b) { return (a + b - 1) / b; }

extern "C" void kernel_launch(void* const* d_in, const int* in_sizes, int n_in,
                              void* d_out, int out_size, void* d_ws, size_t ws_size,
                              hipStream_t stream) {
    const float* x = (const float*)d_in[0];
    const int* ei = (const int*)d_in[1];
    const float* Wl[3] = {(const float*)d_in[2], (const float*)d_in[7], (const float*)d_in[12]};
    const float* bl[3] = {(const float*)d_in[3], (const float*)d_in[8], (const float*)d_in[13]};
    const float* Wr[3] = {(const float*)d_in[4], (const float*)d_in[9], (const float*)d_in[14]};
    const float* gam[3] = {(const float*)d_in[5], (const float*)d_in[10], (const float*)d_in[15]};
    const float* bet[3] = {(const float*)d_in[6], (const float*)d_in[11], (const float*)d_in[16]};

    const int N = in_sizes[0] / 128;  // 100000
    const int E = in_sizes[1] / 2;    // 1600000
    const int Couts[3] = {128, 128, 64};

    // workspace layout (256B-aligned chunks)
    char* base = (char*)d_ws;
    size_t off = 0;
    auto alloc = [&](size_t bytes) -> void* {
        void* ptr = base + off;
        off += (bytes + 255) & ~(size_t)255;
        return ptr;
    };
    bf16* h = (bf16*)alloc((size_t)N * 128 * 2);
    bf16* p = (bf16*)alloc((size_t)N * 128 * 2);
    float* r = (float*)alloc((size_t)N * 128 * 4);
    float* o = (float*)alloc((size_t)N * 128 * 4);
    bf16* w0 = (bf16*)alloc(2 * 128 * 128 * 2);
    bf16* w1 = (bf16*)alloc(2 * 128 * 128 * 2);
    bf16* w2 = (bf16*)alloc(2 * 64 * 128 * 2);
    float* stats = (float*)alloc(3 * 512 * 4);  // per layer: sum[128],sq[128],cA[128],cB[128]
    int* rowptr = (int*)alloc((size_t)(N + 1) * 4);
    int* cursor = (int*)alloc((size_t)N * 4);
    int* bsum = (int*)alloc(512 * 4);
    int* ssrc = (int*)alloc((size_t)E * 4);
    bf16* Wc[3] = {w0, w1, w2};

    const int* esrc = ei;
    const int* edst = ei + E;

    // init + conversions
    k_zero<<<cdiv(N, 256), 256, 0, stream>>>(cursor, stats, N, 3 * 512);
    k_cvt_x<<<cdiv(N * 32, 256), 256, 0, stream>>>(x, h, N * 32);
    k_cvt_w<<<cdiv(128 * 128, 256), 256, 0, stream>>>(Wl[0], Wr[0], w0, 128 * 128);
    k_cvt_w<<<cdiv(128 * 128, 256), 256, 0, stream>>>(Wl[1], Wr[1], w1, 128 * 128);
    k_cvt_w<<<cdiv(64 * 128, 256), 256, 0, stream>>>(Wl[2], Wr[2], w2, 64 * 128);

    // CSR build
    k_count<<<cdiv(E, 256), 256, 0, stream>>>(edst, cursor, E);
    int nb = cdiv(N + 1, 256);
    k_scan1<<<nb, 256, 0, stream>>>(cursor, rowptr, bsum, N);
    k_scan2<<<1, 512, 0, stream>>>(bsum, nb);
    k_scan3<<<nb, 256, 0, stream>>>(rowptr, bsum, cursor, N);
    k_scatter<<<cdiv(E, 256), 256, 0, stream>>>(esrc, edst, cursor, ssrc, E);

    // layers
    const int AGG_BLOCKS = 2048;
    const int NWAVES = AGG_BLOCKS * 4;
    for (int l = 0; l < 3; l++) {
        int Cout = Couts[l];
        float* ss = stats + l * 512;
        float* sq = ss + 128;
        float* cA = ss + 256;
        float* cB = ss + 384;
        k_gemm<<<cdiv(N / 16, 4), 256, 0, stream>>>(h, Wc[l], bl[l], p, r, Cout, N);
        k_aggregate<<<AGG_BLOCKS, 256, 0, stream>>>(p, r, rowptr, ssrc, o, ss, sq, Cout, N, NWAVES);
        k_bn_fin<<<1, 128, 0, stream>>>(ss, sq, gam[l], bet[l], cA, cB, Cout, N);
        if (l < 2) {
            k_norm_relu<<<cdiv(N * 32, 256), 256, 0, stream>>>(o, cA, cB, h, N * 32);
        } else {
            k_norm_out<<<cdiv(N * 16, 256), 256, 0, stream>>>(o, cA, cB, (float*)d_out, N * 16);
        }
    }
}